// Round 1
// baseline (267.482 us; speedup 1.0000x reference)
//
#include <hip/hip_runtime.h>
#include <hip/hip_bf16.h>
#include <cstdint>

// ============================================================================
// ScaledDotAttention: out = softmax((Q Wq^T + bq)(K Wk^T + bk)^T / 8) @ V
// B=8, N=4096, DK=512, DM=64.  Strategy: everything in bf16 MFMA.
//   k1 wconv : Wk,Wq fp32 -> bf16
//   k2 vtrans: V fp32 [b][n][512] -> bf16 Vt [b][512][4096]   (transposed)
//   k3 proj  : pq,pk bf16 [b*n][64] via mfma_16x16x32_bf16
//   k4 flash : fused attention, 256 blocks (batch = blockIdx%8 -> XCD-local L2),
//              8 waves x 128 q-rows, KV-step 64, swapped QK^T + swapped PV,
//              P shared via LDS, XOR-swizzled 128B-row LDS tiles staged with
//              global_load_lds (pre-swizzled source, linear dest).
// ============================================================================

#define DEVINL __device__ __forceinline__

using f32x4  = __attribute__((ext_vector_type(4)))  float;
using bf16x8 = __attribute__((ext_vector_type(8)))  short;
using bf16x4 = __attribute__((ext_vector_type(4)))  short;

constexpr int BATCH = 8;
constexpr int N     = 4096;
constexpr int DK    = 512;
constexpr int DM    = 64;
constexpr int KVB   = 64;            // keys per step
constexpr int QB    = 128;           // q rows per block
constexpr int STEPS = N / KVB;       // 64

// fp32 -> bf16 round-to-nearest-even (no NaN handling needed here)
DEVINL short cvt_bf16(float x) {
  uint32_t u = __float_as_uint(x);
  uint32_t r = u + 0x7fffu + ((u >> 16) & 1u);
  return (short)(r >> 16);
}

// async global->LDS, 16B per lane. lds ptr must be wave-uniform (HW adds lane*16).
DEVINL void async16(void* lds, const void* g) {
  __builtin_amdgcn_global_load_lds(
      (const __attribute__((address_space(1))) uint32_t*)(uintptr_t)g,
      (__attribute__((address_space(3))) uint32_t*)(uint32_t)(uintptr_t)lds,
      16, 0, 0);
}

DEVINL f32x4 mfma16(bf16x8 a, bf16x8 b, f32x4 c) {
  return __builtin_amdgcn_mfma_f32_16x16x32_bf16(a, b, c, 0, 0, 0);
}

// ---------------------------------------------------------------------------
__global__ __launch_bounds__(256) void wconv_kernel(
    const float* __restrict__ Wk, const float* __restrict__ Wq,
    short* __restrict__ WkB, short* __restrict__ WqB) {
  int i = blockIdx.x * 256 + threadIdx.x;      // grid covers exactly 64*512
  WkB[i] = cvt_bf16(Wk[i]);
  WqB[i] = cvt_bf16(Wq[i]);
}

// ---------------------------------------------------------------------------
// V [b][n][512] fp32 -> Vt [b][512][4096] bf16, 64x64 tiles through LDS.
__global__ __launch_bounds__(256) void vtrans_kernel(
    const float* __restrict__ V, short* __restrict__ Vt) {
  int bb = blockIdx.x;                 // 8 * 64 * 8 = 4096 blocks
  int b  = bb >> 9;
  int nt = (bb >> 3) & 63;
  int dt = bb & 7;
  int n0 = nt * 64, d0 = dt * 64;
  __shared__ short t_lds[64][80];      // [d][n], padded row (160B, 16B-aligned)
  int tid = threadIdx.x;
#pragma unroll
  for (int it = 0; it < 4; ++it) {
    int idx = it * 256 + tid;          // 0..1023 : 64 rows x 16 f32x4
    int row = idx >> 4;                // n in tile
    int c4  = idx & 15;
    f32x4 v = *(const f32x4*)&V[((size_t)b * N + n0 + row) * DK + d0 + c4 * 4];
#pragma unroll
    for (int j = 0; j < 4; ++j) t_lds[c4 * 4 + j][row] = cvt_bf16(v[j]);
  }
  __syncthreads();
#pragma unroll
  for (int it = 0; it < 2; ++it) {
    int idx = it * 256 + tid;          // 0..511 : 64 rows x 8 chunks(16B)
    int rd = idx >> 3;
    int ck = idx & 7;
    bf16x8 vv = *(const bf16x8*)&t_lds[rd][ck * 8];
    *(bf16x8*)&Vt[((size_t)b * DK + d0 + rd) * N + n0 + ck * 8] = vv;
  }
}

// ---------------------------------------------------------------------------
// pq = Q@Wq^T + bq -> bf16 [32768][64]; same for pk. 512 blocks (first 256 Q).
// Block: 512 thr, 128 rows; X tile staged bf16 in LDS (chunk-XOR swizzle).
__global__ __launch_bounds__(512, 2) void proj_kernel(
    const float* __restrict__ Q, const float* __restrict__ K,
    const short* __restrict__ WqB, const short* __restrict__ WkB,
    const float* __restrict__ bq, const float* __restrict__ bk,
    short* __restrict__ pq, short* __restrict__ pk) {
  bool isK = blockIdx.x >= 256;
  const float* X    = isK ? K : Q;
  const short* W    = isK ? WkB : WqB;
  const float* bias = isK ? bk : bq;
  short* P          = isK ? pk : pq;
  int rb = (blockIdx.x & 255) * 128;

  __shared__ short x_lds[128 * 512];   // 128KB, [row][512] bf16, swizzled chunks
  int tid = threadIdx.x, w = tid >> 6, lane = tid & 63, g = lane >> 4, c = lane & 15;

#pragma unroll
  for (int it = 0; it < 32; ++it) {
    int idx4 = it * 512 + tid;         // 0..16383 f32x4 units
    int row  = idx4 >> 7;
    int col  = (idx4 & 127) * 4;
    f32x4 v = *(const f32x4*)&X[((size_t)rb + row) * DK + col];
    bf16x4 hb;
#pragma unroll
    for (int j = 0; j < 4; ++j) hb[j] = cvt_bf16(v[j]);
    int sc = (col >> 3) ^ (row & 7);   // 16B-chunk XOR swizzle
    *(bf16x4*)&x_lds[row * 512 + sc * 8 + ((col >> 2) & 1) * 4] = hb;
  }
  __syncthreads();

  f32x4 o[4];
#pragma unroll
  for (int mt = 0; mt < 4; ++mt) o[mt] = f32x4{0.f, 0.f, 0.f, 0.f};
  int arow = w * 16 + c;
#pragma unroll
  for (int ks = 0; ks < 16; ++ks) {
    int sc = (ks * 4 + g) ^ (arow & 7);
    bf16x8 a = *(const bf16x8*)&x_lds[arow * 512 + sc * 8];
#pragma unroll
    for (int mt = 0; mt < 4; ++mt) {
      // B[k][n] = W^T : lane holds W[mt*16+c][ks*32 + g*8 + i]
      bf16x8 bfr = *(const bf16x8*)&W[(size_t)(mt * 16 + c) * DK + ks * 32 + g * 8];
      o[mt] = mfma16(a, bfr, o[mt]);
    }
  }
#pragma unroll
  for (int mt = 0; mt < 4; ++mt) {
    float bb = bias[mt * 16 + c];
#pragma unroll
    for (int r = 0; r < 4; ++r) {
      int row = rb + w * 16 + g * 4 + r;     // D row = g*4+r within wave's tile
      P[(size_t)row * DM + mt * 16 + c] = cvt_bf16(o[mt][r] + bb);
    }
  }
}

// ---------------------------------------------------------------------------
// Fused flash attention.
__global__ __launch_bounds__(512, 2) void flash_kernel(
    const short* __restrict__ pq, const short* __restrict__ pk,
    const short* __restrict__ vt, float* __restrict__ out) {
  int b  = blockIdx.x & 7;             // batch -> XCD (L2-local Vt)
  int qt = blockIdx.x >> 3;            // 0..31
  int q0 = qt * QB;

  int tid = threadIdx.x, w = tid >> 6, lane = tid & 63, g = lane >> 4, c = lane & 15;

  __shared__ short pk_lds[KVB * DM];        //  8KB [key][64dm]
  __shared__ short vt_lds[2][DK * KVB];     // 128KB [vcol][64key] dbuf
  __shared__ short p_lds[QB * KVB];         // 16KB [q][64key]
  __shared__ float alpha_lds[QB];
  __shared__ float lsum_lds[QB];

  const short* pk_b = pk + (size_t)b * N * DM;
  const short* vt_b = vt + (size_t)b * DK * N;

  // pq fragments for this wave's q-slice (q = q0 + w*16 + c), B-operand layout
  const short* pq_row = pq + ((size_t)b * N + q0 + w * 16 + c) * DM;
  bf16x8 qf0 = *(const bf16x8*)(pq_row + g * 8);
  bf16x8 qf1 = *(const bf16x8*)(pq_row + 32 + g * 8);

  f32x4 acc[4][8];                     // [vcol-tile][q-tile], wave cols w*64..+63
#pragma unroll
  for (int i = 0; i < 4; ++i)
#pragma unroll
    for (int j = 0; j < 8; ++j) acc[i][j] = f32x4{0.f, 0.f, 0.f, 0.f};

  float m_run = -1e30f, l_run = 0.f;

  auto stage_pk = [&](int t) {
    int off16 = tid;                   // 512 x 16B = 8KB tile
    int row = off16 >> 3, ck = off16 & 7;
    const short* src = pk_b + (size_t)(t * KVB + row) * DM + ((ck ^ (row & 7)) * 8);
    async16((void*)(pk_lds + (size_t)w * 512), (const void*)src);
  };
  auto stage_vt = [&](int t, int buf) {
#pragma unroll
    for (int r = 0; r < 8; ++r) {      // 8 x 8KB = 64KB tile
      int off16 = r * 512 + tid;
      int row = off16 >> 3, ck = off16 & 7;   // row = vcol
      const short* src = vt_b + (size_t)row * N + t * KVB + ((ck ^ (row & 7)) * 8);
      async16((void*)(&vt_lds[buf][0] + (size_t)(r * 512 + w * 64) * 8), (const void*)src);
    }
  };

  stage_pk(0);
  stage_vt(0, 0);
  __syncthreads();                     // full drain

  for (int t = 0; t < STEPS; ++t) {
    int buf = t & 1;
    if (t + 1 < STEPS) stage_vt(t + 1, buf ^ 1);   // overlaps whole step

    // ---- QK^T (swapped): S^T[key][q], A = pk tile, B = pq frags ----
    float sv[16];
#pragma unroll
    for (int s = 0; s < 4; ++s) {
      int row = s * 16 + c;            // key row in tile
      bf16x8 a0 = *(const bf16x8*)&pk_lds[row * 64 + ((g ^ (row & 7)) * 8)];
      bf16x8 a1 = *(const bf16x8*)&pk_lds[row * 64 + (((4 + g) ^ (row & 7)) * 8)];
      f32x4 d = f32x4{0.f, 0.f, 0.f, 0.f};
      d = mfma16(a0, qf0, d);
      d = mfma16(a1, qf1, d);
#pragma unroll
      for (int r = 0; r < 4; ++r) sv[s * 4 + r] = d[r] * 0.125f;  // scale=1/sqrt(64)
    }

    // ---- online softmax for q = q0 + w*16 + c (keys t*64 + s*16 + g*4 + r) ----
    float tmax = sv[0];
#pragma unroll
    for (int j = 1; j < 16; ++j) tmax = fmaxf(tmax, sv[j]);
    tmax = fmaxf(tmax, __shfl_xor(tmax, 16));
    tmax = fmaxf(tmax, __shfl_xor(tmax, 32));
    float m_new = fmaxf(m_run, tmax);
    float alpha = __expf(m_run - m_new);
    float ts = 0.f;
#pragma unroll
    for (int j = 0; j < 16; ++j) { sv[j] = __expf(sv[j] - m_new); ts += sv[j]; }
    ts += __shfl_xor(ts, 16);
    ts += __shfl_xor(ts, 32);
    l_run = l_run * alpha + ts;
    m_run = m_new;

    int qrow = w * 16 + c;
    if (g == 0) alpha_lds[qrow] = alpha;
#pragma unroll
    for (int s = 0; s < 4; ++s) {      // P[q][key], 4 bf16 per write
      bf16x4 pb;
#pragma unroll
      for (int r = 0; r < 4; ++r) pb[r] = cvt_bf16(sv[s * 4 + r]);
      int ck = (s * 2 + (g >> 1)) ^ (qrow & 7);
      *(bf16x4*)&p_lds[qrow * 64 + ck * 8 + (g & 1) * 4] = pb;
    }

    // mid barrier: LDS writes visible; staged vt loads stay in flight
    asm volatile("s_waitcnt lgkmcnt(0)" ::: "memory");
    __builtin_amdgcn_s_barrier();
    asm volatile("" ::: "memory");

    if (t + 1 < STEPS) stage_pk(t + 1);      // single pk buffer, safe post-barrier

    // ---- rescale acc by alpha of each q-tile ----
    float al[8];
#pragma unroll
    for (int j = 0; j < 8; ++j) al[j] = alpha_lds[j * 16 + c];
#pragma unroll
    for (int i = 0; i < 4; ++i)
#pragma unroll
      for (int j = 0; j < 8; ++j) acc[i][j] *= al[j];

    // ---- PV (swapped): acc[vcol][q] += V^T tile @ P^T tile ----
#pragma unroll
    for (int kh = 0; kh < 2; ++kh) {
      bf16x8 pf[8];
#pragma unroll
      for (int j = 0; j < 8; ++j) {
        int row = j * 16 + c;          // q row
        pf[j] = *(const bf16x8*)&p_lds[row * 64 + (((kh * 4 + g) ^ (row & 7)) * 8)];
      }
#pragma unroll
      for (int i = 0; i < 4; ++i) {
        int row = w * 64 + i * 16 + c; // vcol row
        bf16x8 vf = *(const bf16x8*)&vt_lds[buf][row * 64 + (((kh * 4 + g) ^ (row & 7)) * 8)];
#pragma unroll
        for (int j = 0; j < 8; ++j) acc[i][j] = mfma16(vf, pf[j], acc[i][j]);
      }
    }
    __syncthreads();                   // drains staged loads for next step
  }

  if (g == 0) lsum_lds[w * 16 + c] = l_run;
  __syncthreads();

  float* out_b = out + (size_t)b * N * DK;
#pragma unroll
  for (int j = 0; j < 8; ++j) {
    float rl = 1.f / lsum_lds[j * 16 + c];
#pragma unroll
    for (int i = 0; i < 4; ++i)
#pragma unroll
      for (int r = 0; r < 4; ++r) {
        int q    = q0 + j * 16 + c;
        int vcol = w * 64 + i * 16 + g * 4 + r;
        out_b[(size_t)q * DK + vcol] = acc[i][j][r] * rl;
      }
  }
}

// ---------------------------------------------------------------------------
extern "C" void kernel_launch(void* const* d_in, const int* in_sizes, int n_in,
                              void* d_out, int out_size, void* d_ws, size_t ws_size,
                              hipStream_t stream) {
  (void)in_sizes; (void)n_in; (void)out_size; (void)ws_size;
  const float* K  = (const float*)d_in[0];
  const float* Q  = (const float*)d_in[1];
  const float* V  = (const float*)d_in[2];
  const float* Wk = (const float*)d_in[3];
  const float* bk = (const float*)d_in[4];
  const float* Wq = (const float*)d_in[5];
  const float* bq = (const float*)d_in[6];
  float* out = (float*)d_out;

  char* ws = (char*)d_ws;
  short* pq  = (short*)(ws + 0);                         //  4MB [32768][64]
  short* pk  = (short*)(ws + ((size_t)4 << 20));         //  4MB
  short* vt  = (short*)(ws + ((size_t)8 << 20));         // 32MB [8][512][4096]
  short* WqB = (short*)(ws + ((size_t)40 << 20));        // 64KB
  short* WkB = (short*)(ws + ((size_t)40 << 20) + 64 * 512 * 2);

  hipLaunchKernelGGL(wconv_kernel,  dim3(128),  dim3(256), 0, stream, Wk, Wq, WkB, WqB);
  hipLaunchKernelGGL(vtrans_kernel, dim3(4096), dim3(256), 0, stream, V, vt);
  hipLaunchKernelGGL(proj_kernel,   dim3(512),  dim3(512), 0, stream, Q, K, WqB, WkB, bq, bk, pq, pk);
  hipLaunchKernelGGL(flash_kernel,  dim3(256),  dim3(512), 0, stream, pq, pk, vt, out);
}

// Round 2
// 248.704 us; speedup vs baseline: 1.0755x; 1.0755x over previous
//
#include <hip/hip_runtime.h>
#include <hip/hip_bf16.h>
#include <cstdint>

// ============================================================================
// ScaledDotAttention: out = softmax((Q Wq^T + bq)(K Wk^T + bk)^T / 8) @ V
// B=8, N=4096, DK=512, DM=64.
// R2: single-region pipelined flash step (counted vmcnt, no per-step vm drain),
//     defer-max rescale (THR=8), softmax striped between PV MFMA halves,
//     score scale folded into Q projection.
// ============================================================================

#define DEVINL __device__ __forceinline__

using f32x4  = __attribute__((ext_vector_type(4)))  float;
using bf16x8 = __attribute__((ext_vector_type(8)))  short;
using bf16x4 = __attribute__((ext_vector_type(4)))  short;

constexpr int BATCH = 8;
constexpr int N     = 4096;
constexpr int DK    = 512;
constexpr int DM    = 64;
constexpr int KVB   = 64;            // keys per step
constexpr int QB    = 128;           // q rows per block
constexpr int STEPS = N / KVB;       // 64

DEVINL short cvt_bf16(float x) {
  uint32_t u = __float_as_uint(x);
  uint32_t r = u + 0x7fffu + ((u >> 16) & 1u);
  return (short)(r >> 16);
}

DEVINL void async16(void* lds, const void* g) {
  __builtin_amdgcn_global_load_lds(
      (const __attribute__((address_space(1))) uint32_t*)(uintptr_t)g,
      (__attribute__((address_space(3))) uint32_t*)(uint32_t)(uintptr_t)lds,
      16, 0, 0);
}

DEVINL f32x4 mfma16(bf16x8 a, bf16x8 b, f32x4 c) {
  return __builtin_amdgcn_mfma_f32_16x16x32_bf16(a, b, c, 0, 0, 0);
}

// ---------------------------------------------------------------------------
__global__ __launch_bounds__(256) void wconv_kernel(
    const float* __restrict__ Wk, const float* __restrict__ Wq,
    short* __restrict__ WkB, short* __restrict__ WqB) {
  int i = blockIdx.x * 256 + threadIdx.x;
  WkB[i] = cvt_bf16(Wk[i]);
  WqB[i] = cvt_bf16(Wq[i]);
}

// ---------------------------------------------------------------------------
__global__ __launch_bounds__(256) void vtrans_kernel(
    const float* __restrict__ V, short* __restrict__ Vt) {
  int bb = blockIdx.x;
  int b  = bb >> 9;
  int nt = (bb >> 3) & 63;
  int dt = bb & 7;
  int n0 = nt * 64, d0 = dt * 64;
  __shared__ short t_lds[64][80];
  int tid = threadIdx.x;
#pragma unroll
  for (int it = 0; it < 4; ++it) {
    int idx = it * 256 + tid;
    int row = idx >> 4;
    int c4  = idx & 15;
    f32x4 v = *(const f32x4*)&V[((size_t)b * N + n0 + row) * DK + d0 + c4 * 4];
#pragma unroll
    for (int j = 0; j < 4; ++j) t_lds[c4 * 4 + j][row] = cvt_bf16(v[j]);
  }
  __syncthreads();
#pragma unroll
  for (int it = 0; it < 2; ++it) {
    int idx = it * 256 + tid;
    int rd = idx >> 3;
    int ck = idx & 7;
    bf16x8 vv = *(const bf16x8*)&t_lds[rd][ck * 8];
    *(bf16x8*)&Vt[((size_t)b * DK + d0 + rd) * N + n0 + ck * 8] = vv;
  }
}

// ---------------------------------------------------------------------------
// pq = (Q@Wq^T + bq)/8 -> bf16 (scale folded here); pk = K@Wk^T + bk -> bf16.
__global__ __launch_bounds__(512, 2) void proj_kernel(
    const float* __restrict__ Q, const float* __restrict__ K,
    const short* __restrict__ WqB, const short* __restrict__ WkB,
    const float* __restrict__ bq, const float* __restrict__ bk,
    short* __restrict__ pq, short* __restrict__ pk) {
  bool isK = blockIdx.x >= 256;
  const float* X    = isK ? K : Q;
  const short* W    = isK ? WkB : WqB;
  const float* bias = isK ? bk : bq;
  short* P          = isK ? pk : pq;
  float sc          = isK ? 1.0f : 0.125f;
  int rb = (blockIdx.x & 255) * 128;

  __shared__ short x_lds[128 * 512];
  int tid = threadIdx.x, w = tid >> 6, lane = tid & 63, g = lane >> 4, c = lane & 15;

#pragma unroll
  for (int it = 0; it < 32; ++it) {
    int idx4 = it * 512 + tid;
    int row  = idx4 >> 7;
    int col  = (idx4 & 127) * 4;
    f32x4 v = *(const f32x4*)&X[((size_t)rb + row) * DK + col];
    bf16x4 hb;
#pragma unroll
    for (int j = 0; j < 4; ++j) hb[j] = cvt_bf16(v[j]);
    int scz = (col >> 3) ^ (row & 7);
    *(bf16x4*)&x_lds[row * 512 + scz * 8 + ((col >> 2) & 1) * 4] = hb;
  }
  __syncthreads();

  f32x4 o[4];
#pragma unroll
  for (int mt = 0; mt < 4; ++mt) o[mt] = f32x4{0.f, 0.f, 0.f, 0.f};
  int arow = w * 16 + c;
#pragma unroll
  for (int ks = 0; ks < 16; ++ks) {
    int scz = (ks * 4 + g) ^ (arow & 7);
    bf16x8 a = *(const bf16x8*)&x_lds[arow * 512 + scz * 8];
#pragma unroll
    for (int mt = 0; mt < 4; ++mt) {
      bf16x8 bfr = *(const bf16x8*)&W[(size_t)(mt * 16 + c) * DK + ks * 32 + g * 8];
      o[mt] = mfma16(a, bfr, o[mt]);
    }
  }
#pragma unroll
  for (int mt = 0; mt < 4; ++mt) {
    float bb = bias[mt * 16 + c];
#pragma unroll
    for (int r = 0; r < 4; ++r) {
      int row = rb + w * 16 + g * 4 + r;
      P[(size_t)row * DM + mt * 16 + c] = cvt_bf16((o[mt][r] + bb) * sc);
    }
  }
}

// ---------------------------------------------------------------------------
// Fused flash attention, single-region pipelined step.
__global__ __launch_bounds__(512, 2) void flash_kernel(
    const short* __restrict__ pq, const short* __restrict__ pk,
    const short* __restrict__ vt, float* __restrict__ out) {
  int b  = blockIdx.x & 7;             // batch -> XCD (L2-local Vt)
  int qt = blockIdx.x >> 3;
  int q0 = qt * QB;

  int tid = threadIdx.x, w = tid >> 6, lane = tid & 63, g = lane >> 4, c = lane & 15;
  int qrow = w * 16 + c;

  __shared__ short pk_lds[KVB * DM];        //  8KB, single buffer
  __shared__ short vt_lds[2][DK * KVB];     // 128KB dbuf
  __shared__ short p_lds[QB * KVB];         // 16KB, single buffer
  __shared__ float alpha_lds[QB];
  __shared__ float lsum_lds[QB];

  const short* pk_b = pk + (size_t)b * N * DM;
  const short* vt_b = vt + (size_t)b * DK * N;

  const short* pq_row = pq + ((size_t)b * N + q0 + qrow) * DM;
  bf16x8 qf0 = *(const bf16x8*)(pq_row + g * 8);
  bf16x8 qf1 = *(const bf16x8*)(pq_row + 32 + g * 8);

  f32x4 acc[4][8];
#pragma unroll
  for (int i = 0; i < 4; ++i)
#pragma unroll
    for (int j = 0; j < 8; ++j) acc[i][j] = f32x4{0.f, 0.f, 0.f, 0.f};

  float m_run = -1e30f, l_run = 0.f;

  auto stage_pk = [&](int t) {
    int row = tid >> 3, ck = tid & 7;
    const short* src = pk_b + (size_t)(t * KVB + row) * DM + ((ck ^ (row & 7)) * 8);
    async16((void*)(pk_lds + (size_t)w * 512), (const void*)src);
  };
  auto stage_vt = [&](int t, int buf) {
#pragma unroll
    for (int r = 0; r < 8; ++r) {
      int off16 = r * 512 + tid;
      int row = off16 >> 3, ck = off16 & 7;
      const short* src = vt_b + (size_t)row * N + t * KVB + ((ck ^ (row & 7)) * 8);
      async16((void*)(&vt_lds[buf][0] + (size_t)(r * 512 + w * 64) * 8), (const void*)src);
    }
  };

  // ======================= prolog: stage + QKT(0)/P(0) ======================
  stage_pk(0);
  stage_vt(0, 0);
  __syncthreads();                     // full drain

  float sv[16];
  bf16x4 pb[4];
  float alpha;
  {
#pragma unroll
    for (int s = 0; s < 4; ++s) {
      int row = s * 16 + c;
      bf16x8 a0 = *(const bf16x8*)&pk_lds[row * 64 + ((g ^ (row & 7)) * 8)];
      bf16x8 a1 = *(const bf16x8*)&pk_lds[row * 64 + (((4 + g) ^ (row & 7)) * 8)];
      f32x4 d = f32x4{0.f, 0.f, 0.f, 0.f};
      d = mfma16(a0, qf0, d);
      d = mfma16(a1, qf1, d);
#pragma unroll
      for (int r = 0; r < 4; ++r) sv[s * 4 + r] = d[r];
    }
    float tmax = sv[0];
#pragma unroll
    for (int j = 1; j < 16; ++j) tmax = fmaxf(tmax, sv[j]);
    tmax = fmaxf(tmax, __shfl_xor(tmax, 16));
    tmax = fmaxf(tmax, __shfl_xor(tmax, 32));
    m_run = tmax;
    float ts = 0.f;
#pragma unroll
    for (int j = 0; j < 16; ++j) { sv[j] = __expf(sv[j] - m_run); ts += sv[j]; }
    ts += __shfl_xor(ts, 16);
    ts += __shfl_xor(ts, 32);
    l_run = ts;
    alpha = 1.0f;                      // acc == 0, no rescale needed
#pragma unroll
    for (int s = 0; s < 4; ++s)
#pragma unroll
      for (int r = 0; r < 4; ++r) pb[s][r] = cvt_bf16(sv[s * 4 + r]);
  }
  asm volatile("s_waitcnt lgkmcnt(0)" ::: "memory");
  __builtin_amdgcn_s_barrier();        // pk reads done in all waves
#pragma unroll
  for (int s = 0; s < 4; ++s) {
    int ck = (s * 2 + (g >> 1)) ^ (qrow & 7);
    *(bf16x4*)&p_lds[qrow * 64 + ck * 8 + (g & 1) * 4] = pb[s];
  }
  if (g == 0) alpha_lds[qrow] = alpha;
  stage_pk(1);
  asm volatile("s_waitcnt lgkmcnt(0)" ::: "memory");
  __builtin_amdgcn_s_barrier();
  __builtin_amdgcn_sched_barrier(0);

  // ===================== main loop: PV(t) + QKT(t+1) ========================
  for (int t = 0; t < STEPS - 1; ++t) {
    int vb = t & 1;
    stage_vt(t + 1, vb ^ 1);           // 8 vm ops, in flight across the step
    asm volatile("s_waitcnt vmcnt(8)" ::: "memory");   // vt(t) + pk(t+1) done
    __builtin_amdgcn_sched_barrier(0);

    // rescale-check for step t (alpha written last iter; almost always all 1)
    {
      float al[8];
      bool ne = false;
#pragma unroll
      for (int j = 0; j < 8; ++j) { al[j] = alpha_lds[j * 16 + c]; ne |= (al[j] != 1.0f); }
      if (__any(ne)) {
#pragma unroll
        for (int i = 0; i < 4; ++i)
#pragma unroll
          for (int j = 0; j < 8; ++j) acc[i][j] *= al[j];
      }
    }

    // ---- QKT(t+1) ----
#pragma unroll
    for (int s = 0; s < 4; ++s) {
      int row = s * 16 + c;
      bf16x8 a0 = *(const bf16x8*)&pk_lds[row * 64 + ((g ^ (row & 7)) * 8)];
      bf16x8 a1 = *(const bf16x8*)&pk_lds[row * 64 + (((4 + g) ^ (row & 7)) * 8)];
      f32x4 d = f32x4{0.f, 0.f, 0.f, 0.f};
      d = mfma16(a0, qf0, d);
      d = mfma16(a1, qf1, d);
#pragma unroll
      for (int r = 0; r < 4; ++r) sv[s * 4 + r] = d[r];
    }

    // ---- softmax p1: running max (defer-max THR=8) ----
    float tmax = sv[0];
#pragma unroll
    for (int j = 1; j < 16; ++j) tmax = fmaxf(tmax, sv[j]);
    tmax = fmaxf(tmax, __shfl_xor(tmax, 16));
    tmax = fmaxf(tmax, __shfl_xor(tmax, 32));
    alpha = 1.0f;
    if (tmax > m_run + 8.0f) {
      alpha = __expf(m_run - tmax);
      m_run = tmax;
    }

    // ---- PV(t) kh=0 ----
    __builtin_amdgcn_s_setprio(1);
    {
      bf16x8 pf[8];
#pragma unroll
      for (int j = 0; j < 8; ++j) {
        int row = j * 16 + c;
        pf[j] = *(const bf16x8*)&p_lds[row * 64 + ((g ^ (row & 7)) * 8)];
      }
#pragma unroll
      for (int i = 0; i < 4; ++i) {
        int row = w * 64 + i * 16 + c;
        bf16x8 vf = *(const bf16x8*)&vt_lds[vb][row * 64 + ((g ^ (row & 7)) * 8)];
#pragma unroll
        for (int j = 0; j < 8; ++j) acc[i][j] = mfma16(vf, pf[j], acc[i][j]);
      }
    }
    __builtin_amdgcn_s_setprio(0);

    // ---- softmax p2: exp + partial sum ----
    float ts = 0.f;
#pragma unroll
    for (int j = 0; j < 16; ++j) { sv[j] = __expf(sv[j] - m_run); ts += sv[j]; }

    // ---- PV(t) kh=1 ----
    __builtin_amdgcn_s_setprio(1);
    {
      bf16x8 pf[8];
#pragma unroll
      for (int j = 0; j < 8; ++j) {
        int row = j * 16 + c;
        pf[j] = *(const bf16x8*)&p_lds[row * 64 + (((4 + g) ^ (row & 7)) * 8)];
      }
#pragma unroll
      for (int i = 0; i < 4; ++i) {
        int row = w * 64 + i * 16 + c;
        bf16x8 vf = *(const bf16x8*)&vt_lds[vb][row * 64 + (((4 + g) ^ (row & 7)) * 8)];
#pragma unroll
        for (int j = 0; j < 8; ++j) acc[i][j] = mfma16(vf, pf[j], acc[i][j]);
      }
    }
    __builtin_amdgcn_s_setprio(0);

    // ---- softmax p3: sum reduce, l update, pack ----
    ts += __shfl_xor(ts, 16);
    ts += __shfl_xor(ts, 32);
    l_run = l_run * alpha + ts;
#pragma unroll
    for (int s = 0; s < 4; ++s)
#pragma unroll
      for (int r = 0; r < 4; ++r) pb[s][r] = cvt_bf16(sv[s * 4 + r]);

    asm volatile("s_waitcnt lgkmcnt(0)" ::: "memory");
    __builtin_amdgcn_s_barrier();      // all p_lds/pk_lds reads of this iter done
    __builtin_amdgcn_sched_barrier(0);

    // ---- region B: publish P(t+1), alpha(t+1); stage pk(t+2) ----
#pragma unroll
    for (int s = 0; s < 4; ++s) {
      int ck = (s * 2 + (g >> 1)) ^ (qrow & 7);
      *(bf16x4*)&p_lds[qrow * 64 + ck * 8 + (g & 1) * 4] = pb[s];
    }
    if (g == 0) alpha_lds[qrow] = alpha;
    if (t < STEPS - 2) stage_pk(t + 2);
    asm volatile("s_waitcnt lgkmcnt(0)" ::: "memory");
    __builtin_amdgcn_s_barrier();
    __builtin_amdgcn_sched_barrier(0);
  }

  // ============================== epilog: PV(63) ============================
  asm volatile("s_waitcnt vmcnt(0)" ::: "memory");
  __builtin_amdgcn_sched_barrier(0);
  {
    float al[8];
    bool ne = false;
#pragma unroll
    for (int j = 0; j < 8; ++j) { al[j] = alpha_lds[j * 16 + c]; ne |= (al[j] != 1.0f); }
    if (__any(ne)) {
#pragma unroll
      for (int i = 0; i < 4; ++i)
#pragma unroll
        for (int j = 0; j < 8; ++j) acc[i][j] *= al[j];
    }
  }
  {
    int vb = (STEPS - 1) & 1;
#pragma unroll
    for (int kh = 0; kh < 2; ++kh) {
      bf16x8 pf[8];
#pragma unroll
      for (int j = 0; j < 8; ++j) {
        int row = j * 16 + c;
        pf[j] = *(const bf16x8*)&p_lds[row * 64 + (((kh * 4 + g) ^ (row & 7)) * 8)];
      }
#pragma unroll
      for (int i = 0; i < 4; ++i) {
        int row = w * 64 + i * 16 + c;
        bf16x8 vf = *(const bf16x8*)&vt_lds[vb][row * 64 + (((kh * 4 + g) ^ (row & 7)) * 8)];
#pragma unroll
        for (int j = 0; j < 8; ++j) acc[i][j] = mfma16(vf, pf[j], acc[i][j]);
      }
    }
  }

  if (g == 0) lsum_lds[qrow] = l_run;
  asm volatile("s_waitcnt lgkmcnt(0)" ::: "memory");
  __builtin_amdgcn_s_barrier();

  float* out_b = out + (size_t)b * N * DK;
#pragma unroll
  for (int j = 0; j < 8; ++j) {
    float rl = 1.f / lsum_lds[j * 16 + c];
#pragma unroll
    for (int i = 0; i < 4; ++i)
#pragma unroll
      for (int r = 0; r < 4; ++r) {
        int q    = q0 + j * 16 + c;
        int vcol = w * 64 + i * 16 + g * 4 + r;
        out_b[(size_t)q * DK + vcol] = acc[i][j][r] * rl;
      }
  }
}

// ---------------------------------------------------------------------------
extern "C" void kernel_launch(void* const* d_in, const int* in_sizes, int n_in,
                              void* d_out, int out_size, void* d_ws, size_t ws_size,
                              hipStream_t stream) {
  (void)in_sizes; (void)n_in; (void)out_size; (void)ws_size;
  const float* K  = (const float*)d_in[0];
  const float* Q  = (const float*)d_in[1];
  const float* V  = (const float*)d_in[2];
  const float* Wk = (const float*)d_in[3];
  const float* bk = (const float*)d_in[4];
  const float* Wq = (const float*)d_in[5];
  const float* bq = (const float*)d_in[6];
  float* out = (float*)d_out;

  char* ws = (char*)d_ws;
  short* pq  = (short*)(ws + 0);
  short* pk  = (short*)(ws + ((size_t)4 << 20));
  short* vt  = (short*)(ws + ((size_t)8 << 20));
  short* WqB = (short*)(ws + ((size_t)40 << 20));
  short* WkB = (short*)(ws + ((size_t)40 << 20) + 64 * 512 * 2);

  hipLaunchKernelGGL(wconv_kernel,  dim3(128),  dim3(256), 0, stream, Wk, Wq, WkB, WqB);
  hipLaunchKernelGGL(vtrans_kernel, dim3(4096), dim3(256), 0, stream, V, vt);
  hipLaunchKernelGGL(proj_kernel,   dim3(512),  dim3(512), 0, stream, Q, K, WqB, WkB, bq, bk, pq, pk);
  hipLaunchKernelGGL(flash_kernel,  dim3(256),  dim3(512), 0, stream, pq, pk, vt, out);
}